// Round 1
// baseline (1325.153 us; speedup 1.0000x reference)
//
#include <hip/hip_runtime.h>
#include <hip/hip_bf16.h>
#include <math.h>

// DeepseekV2-Lite decoder layer, MI355X gfx950.
// Round 5: fast-math intrinsics (__expf / __sincosf) in attention softmax,
// silu epilogue, rope; wave-uniform causal fast path for interior k-tiles;
// Wq+Wkva merged into one GEMM (contiguous weight slots, split epilogue).
//
// Shapes: B=2 S=2048 T=4096, H=16, D_NOPE=128 D_ROPE=64 D_Q=192 D_V=128,
// KV_RANK=512, HID=2048, INTER=10944.

typedef short short8 __attribute__((ext_vector_type(8)));
typedef short short4v __attribute__((ext_vector_type(4)));
typedef float f32x4 __attribute__((ext_vector_type(4)));

static __device__ __forceinline__ float bf2f(ushort u) {
  union { uint i; float f; } v; v.i = ((uint)u) << 16; return v.f;
}
static __device__ __forceinline__ ushort f2bf(float x) {
  union { float f; uint i; } v; v.f = x;
  uint r = v.i + 0x7fffu + ((v.i >> 16) & 1u);
  return (ushort)(r >> 16);
}

// async global->LDS, 16B per lane; LDS dest is wave-uniform base + lane*16
static __device__ __forceinline__ void glds16(const ushort* g, ushort* l) {
  __builtin_amdgcn_global_load_lds(
      (const __attribute__((address_space(1))) unsigned int*)g,
      (__attribute__((address_space(3))) unsigned int*)l, 16, 0, 0);
}

// ---------------- fp32 -> bf16 weight conversion ----------------
__global__ __launch_bounds__(256)
void cvt_bf16(const float* __restrict__ in, ushort* __restrict__ out, int n8) {
  int i = blockIdx.x * 256 + threadIdx.x;
  if (i >= n8) return;
  float4 a = ((const float4*)in)[2 * i];
  float4 b = ((const float4*)in)[2 * i + 1];
  short8 o;
  o[0] = (short)f2bf(a.x); o[1] = (short)f2bf(a.y);
  o[2] = (short)f2bf(a.z); o[3] = (short)f2bf(a.w);
  o[4] = (short)f2bf(b.x); o[5] = (short)f2bf(b.y);
  o[6] = (short)f2bf(b.z); o[7] = (short)f2bf(b.w);
  ((short8*)out)[i] = o;
}

// ---------------- RMSNorm (fp32 in -> bf16 out) ----------------
__global__ __launch_bounds__(256)
void rms_bf16(const float* __restrict__ in, int istride, int width, float inv_w,
              const float* __restrict__ w, ushort* __restrict__ out, int ostride) {
  const int row = blockIdx.x;
  const float* x = in + (size_t)row * istride;
  float ss = 0.f;
  for (int i = threadIdx.x; i < width; i += 256) { float v = x[i]; ss += v * v; }
#pragma unroll
  for (int off = 32; off > 0; off >>= 1) ss += __shfl_xor(ss, off);
  __shared__ float red[4];
  if ((threadIdx.x & 63) == 0) red[threadIdx.x >> 6] = ss;
  __syncthreads();
  float tot = red[0] + red[1] + red[2] + red[3];
  float scale = rsqrtf(tot * inv_w + 1e-6f);
  ushort* o = out + (size_t)row * ostride;
  for (int i = threadIdx.x; i < width; i += 256) o[i] = f2bf(x[i] * scale * w[i]);
}

// ---------------- GEMM: C[M,N] = A[M,K](bf16) @ B[N,K]^T(bf16) ----------------
// BK=64, XOR-swizzled LDS: slot (row, s) holds global 16B-unit s ^ (row & 7).
// EPI 0: C bf16 ; EPI 1: C f32 ; EPI 2: C f32 = acc + res(f32)
// EPI 3: C bf16 = silu(prev bf16 at Cv) * acc
// EPI 4: split QKV epilogue — cols [0,3072) -> bf16 q (stride 3072);
//        cols [3072,3648) -> f32 ckv (stride 576), resv = ckv base
template<int EPI>
__global__ __launch_bounds__(256, 2)
void gemm_as(const ushort* __restrict__ A, const ushort* __restrict__ B,
             void* __restrict__ Cv, const void* __restrict__ resv,
             int M, int N, int K) {
  __shared__ ushort As[128 * 64];   // 16 KB
  __shared__ ushort Bs[128 * 64];   // 16 KB
  const int tid = threadIdx.x;
  const int wave = tid >> 6, lane = tid & 63;
  const int m0 = blockIdx.x * 128, n0 = blockIdx.y * 128;
  const int lm = lane & 15, quad = lane >> 4;
  const int wm = (wave & 1) * 64, wn = (wave >> 1) * 64;

  const int lrow = lane >> 3;
  const int lcq  = lane & 7;
  const int gu   = lcq ^ lrow;
  const ushort* gA[4];
  const ushort* gB[4];
  ushort* lA[4];
  ushort* lB[4];
#pragma unroll
  for (int j = 0; j < 4; ++j) {
    const int r = wave * 32 + j * 8 + lrow;
    gA[j] = A + (size_t)(m0 + r) * K + gu * 8;
    int br = n0 + r; if (br > N - 1) br = N - 1;   // clamp OOB (garbage ok, cols guarded)
    gB[j] = B + (size_t)br * K + gu * 8;
    lA[j] = &As[(wave * 32 + j * 8) * 64];
    lB[j] = &Bs[(wave * 32 + j * 8) * 64];
  }

  f32x4 acc[4][4];
  const f32x4 z4 = {0.f, 0.f, 0.f, 0.f};
#pragma unroll
  for (int i = 0; i < 4; ++i)
#pragma unroll
    for (int j = 0; j < 4; ++j) acc[i][j] = z4;

  const int sw = lm & 7;   // read-side XOR key

  for (int k0 = 0; k0 < K; k0 += 64) {
#pragma unroll
    for (int j = 0; j < 4; ++j) glds16(gA[j] + k0, lA[j]);
#pragma unroll
    for (int j = 0; j < 4; ++j) glds16(gB[j] + k0, lB[j]);
    __syncthreads();

#pragma unroll
    for (int kk = 0; kk < 2; ++kk) {
      const int us = ((kk * 4 + quad) ^ sw) * 8;
      short8 afr[4], bfr[4];
#pragma unroll
      for (int mt = 0; mt < 4; ++mt)
        afr[mt] = *(const short8*)&As[(wm + mt * 16 + lm) * 64 + us];
#pragma unroll
      for (int nt = 0; nt < 4; ++nt)
        bfr[nt] = *(const short8*)&Bs[(wn + nt * 16 + lm) * 64 + us];
#pragma unroll
      for (int mt = 0; mt < 4; ++mt)
#pragma unroll
        for (int nt = 0; nt < 4; ++nt)
          acc[mt][nt] = __builtin_amdgcn_mfma_f32_16x16x32_bf16(
              afr[mt], bfr[nt], acc[mt][nt], 0, 0, 0);
    }
    __syncthreads();
  }

  // C/D layout: col = lane&15, row = quad*4 + r   [m89-verified]
#pragma unroll
  for (int mt = 0; mt < 4; ++mt) {
#pragma unroll
    for (int r = 0; r < 4; ++r) {
      const int grow = m0 + wm + mt * 16 + quad * 4 + r;
#pragma unroll
      for (int nt = 0; nt < 4; ++nt) {
        const int gcol = n0 + wn + nt * 16 + lm;
        if (gcol < N) {
          const size_t idx = (size_t)grow * N + gcol;
          float vacc = acc[mt][nt][r];
          if (EPI == 0) {
            ((ushort*)Cv)[idx] = f2bf(vacc);
          } else if (EPI == 1) {
            ((float*)Cv)[idx] = vacc;
          } else if (EPI == 2) {
            ((float*)Cv)[idx] = vacc + ((const float*)resv)[idx];
          } else if (EPI == 3) {
            float gv = bf2f(((const ushort*)resv)[idx]);
            ((ushort*)Cv)[idx] = f2bf(gv / (1.f + __expf(-gv)) * vacc);
          } else {  // EPI 4: split q / ckv
            if (gcol < 3072)
              ((ushort*)Cv)[(size_t)grow * 3072 + gcol] = f2bf(vacc);
            else
              ((float*)resv)[(size_t)grow * 576 + (gcol - 3072)] = vacc;
          }
        }
      }
    }
  }
}

// ---------------- YaRN RoPE ----------------
__global__ __launch_bounds__(64)
void rope_kernel(ushort* __restrict__ q, const float* __restrict__ ckv,
                 const int* __restrict__ pos_ids, ushort* __restrict__ kpe) {
  const int t = blockIdx.x;
  const int j = threadIdx.x;
  const int j2 = j & 31;
  const float ar = (float)j2 * (1.f / 32.f);
  const float fe = exp2f(-ar * 13.287712379549449f);
  const float fi = fe * 0.025f;
  float ramp = ((float)j2 - 10.f) * (1.f / 13.f);
  ramp = fminf(fmaxf(ramp, 0.f), 1.f);
  const float invf = fi * ramp + fe * (1.f - ramp);
  const float ang = (float)pos_ids[t] * invf;
  float s, c;
  __sincosf(ang, &s, &c);
  const bool lo = j < 32;
  {
    const float* kp = ckv + (size_t)t * 576 + 512;
    float x0 = kp[2 * j2], x1 = kp[2 * j2 + 1];
    float o = lo ? (x0 * c - x1 * s) : (x1 * c + x0 * s);
    kpe[(size_t)t * 64 + j] = f2bf(o);
  }
  for (int h = 0; h < 16; ++h) {
    ushort* qp = q + (size_t)t * 3072 + h * 192 + 128;
    float x0 = bf2f(qp[2 * j2]), x1 = bf2f(qp[2 * j2 + 1]);
    float o = lo ? (x0 * c - x1 * s) : (x1 * c + x0 * s);
    __syncthreads();
    qp[j] = f2bf(o);
  }
}

// ---------------- Flash MFMA attention ----------------
__global__ __launch_bounds__(256, 2)
void attn_mfma(const ushort* __restrict__ q, const ushort* __restrict__ kv,
               const ushort* __restrict__ kpe, ushort* __restrict__ out) {
  const int qt = (int)gridDim.x - 1 - (int)blockIdx.x;
  const int bh = blockIdx.y;
  const int b = bh >> 4, h = bh & 15;
  const int tid = threadIdx.x;
  const int wave = tid >> 6, lane = tid & 63;
  const int lm = lane & 15, quad = lane >> 4;
  const int wq = wave * 32;
  const float scale = 0.07216878364870323f;

  __shared__ __align__(16) char smem[62464];
  ushort (*Ks)[200] = (ushort(*)[200])smem;
  ushort (*Vt)[72]  = (ushort(*)[72])(smem + 25600);
  ushort (*Pm)[72]  = (ushort(*)[72])(smem + 44032);
  ushort (*Qs)[200] = (ushort(*)[200])smem;

  const size_t tok0 = (size_t)b * 2048;
  const int q0 = qt * 128;

  {
    const ushort* qbase = q + (tok0 + q0) * 3072 + (size_t)h * 192;
#pragma unroll
    for (int it = 0; it < 12; ++it) {
      int idx = (it * 256 + tid) * 8;
      int row = idx / 192, col = idx % 192;
      *(uint4*)&Qs[row][col] = *(const uint4*)(qbase + (size_t)row * 3072 + col);
    }
  }
  __syncthreads();
  short8 qf[2][6];
#pragma unroll
  for (int mt = 0; mt < 2; ++mt)
#pragma unroll
    for (int kk = 0; kk < 6; ++kk)
      qf[mt][kk] = *(const short8*)&Qs[wq + mt * 16 + lm][kk * 32 + quad * 8];
  __syncthreads();

  f32x4 o[2][8];
  const f32x4 z4 = {0.f, 0.f, 0.f, 0.f};
#pragma unroll
  for (int mt = 0; mt < 2; ++mt)
#pragma unroll
    for (int nt = 0; nt < 8; ++nt) o[mt][nt] = z4;
  float m_run[8], l_run[8];
#pragma unroll
  for (int i = 0; i < 8; ++i) { m_run[i] = -3.0e38f; l_run[i] = 0.f; }

  const int nkt = 2 * qt + 2;
  for (int kt = 0; kt < nkt; ++kt) {
    const int kb = kt * 64;
    {
      const int krow = tid >> 2, kq = tid & 3;
      const ushort* src = kv + ((tok0 + kb + krow) * 16 + h) * 256 + kq * 32;
#pragma unroll
      for (int i = 0; i < 4; ++i)
        *(uint4*)&Ks[krow][kq * 32 + i * 8] = *(const uint4*)(src + i * 8);
      const ushort* psrc = kpe + (tok0 + kb + krow) * 64 + kq * 16;
      *(uint4*)&Ks[krow][128 + kq * 16]     = *(const uint4*)(psrc);
      *(uint4*)&Ks[krow][128 + kq * 16 + 8] = *(const uint4*)(psrc + 8);
      const int kgrp = (tid & 15) * 4, dgrp = (tid >> 4) * 8;
      uint4 vv[4];
#pragma unroll
      for (int i = 0; i < 4; ++i)
        vv[i] = *(const uint4*)(kv + ((tok0 + kb + kgrp + i) * 16 + h) * 256 + 128 + dgrp);
#pragma unroll
      for (int j = 0; j < 8; ++j) {
        short4v w;
#pragma unroll
        for (int i = 0; i < 4; ++i) w[i] = (short)((const ushort*)&vv[i])[j];
        *(short4v*)&Vt[dgrp + j][kgrp] = w;
      }
    }
    __syncthreads();

    f32x4 s_acc[2][4];
#pragma unroll
    for (int mt = 0; mt < 2; ++mt)
#pragma unroll
      for (int nt = 0; nt < 4; ++nt) s_acc[mt][nt] = z4;
#pragma unroll
    for (int kk = 0; kk < 6; ++kk) {
      short8 kf[4];
#pragma unroll
      for (int nt = 0; nt < 4; ++nt)
        kf[nt] = *(const short8*)&Ks[nt * 16 + lm][kk * 32 + quad * 8];
#pragma unroll
      for (int mt = 0; mt < 2; ++mt)
#pragma unroll
        for (int nt = 0; nt < 4; ++nt)
          s_acc[mt][nt] = __builtin_amdgcn_mfma_f32_16x16x32_bf16(
              qf[mt][kk], kf[nt], s_acc[mt][nt], 0, 0, 0);
    }

    // wave-uniform: interior tiles (all keys <= min q-row of this wave) skip mask
    const bool full = (kb + 63) <= (q0 + wq);
#pragma unroll
    for (int mt = 0; mt < 2; ++mt) {
#pragma unroll
      for (int r = 0; r < 4; ++r) {
        const int qg = q0 + wq + mt * 16 + quad * 4 + r;
        float sv[4];
        float rm = -3.0e38f;
        if (full) {
#pragma unroll
          for (int nt = 0; nt < 4; ++nt) {
            float s = s_acc[mt][nt][r] * scale;
            sv[nt] = s;
            rm = fmaxf(rm, s);
          }
        } else {
#pragma unroll
          for (int nt = 0; nt < 4; ++nt) {
            const int key = kb + nt * 16 + lm;
            float s = s_acc[mt][nt][r] * scale;
            s = (key <= qg) ? s : -3.0e38f;
            sv[nt] = s;
            rm = fmaxf(rm, s);
          }
        }
#pragma unroll
        for (int off = 1; off < 16; off <<= 1) rm = fmaxf(rm, __shfl_xor(rm, off));
        const int li = mt * 4 + r;
        const float mnew = fmaxf(m_run[li], rm);
        const float alpha = __expf(m_run[li] - mnew);
        m_run[li] = mnew;
        float rs = 0.f;
        ushort pb[4];
#pragma unroll
        for (int nt = 0; nt < 4; ++nt) {
          float p = __expf(sv[nt] - mnew);
          rs += p;
          pb[nt] = f2bf(p);
        }
#pragma unroll
        for (int off = 1; off < 16; off <<= 1) rs += __shfl_xor(rs, off);
        l_run[li] = l_run[li] * alpha + rs;
#pragma unroll
        for (int nt = 0; nt < 8; ++nt) o[mt][nt][r] *= alpha;
        const int qrow = wq + mt * 16 + quad * 4 + r;
#pragma unroll
        for (int nt = 0; nt < 4; ++nt) Pm[qrow][nt * 16 + lm] = pb[nt];
      }
    }

#pragma unroll
    for (int kt2 = 0; kt2 < 2; ++kt2) {
      short8 pa[2];
#pragma unroll
      for (int mt = 0; mt < 2; ++mt)
        pa[mt] = *(const short8*)&Pm[wq + mt * 16 + lm][kt2 * 32 + quad * 8];
#pragma unroll
      for (int nt = 0; nt < 8; ++nt) {
        short8 vb = *(const short8*)&Vt[nt * 16 + lm][kt2 * 32 + quad * 8];
#pragma unroll
        for (int mt = 0; mt < 2; ++mt)
          o[mt][nt] = __builtin_amdgcn_mfma_f32_16x16x32_bf16(
              pa[mt], vb, o[mt][nt], 0, 0, 0);
      }
    }
    __syncthreads();
  }

  ushort* obase = out + (tok0 + q0) * 2048 + h * 128;
#pragma unroll
  for (int mt = 0; mt < 2; ++mt) {
#pragma unroll
    for (int r = 0; r < 4; ++r) {
      const int qrow = wq + mt * 16 + quad * 4 + r;
      const float inv = 1.f / l_run[mt * 4 + r];
#pragma unroll
      for (int nt = 0; nt < 8; ++nt)
        obase[(size_t)qrow * 2048 + nt * 16 + lm] = f2bf(o[mt][nt][r] * inv);
    }
  }
}

extern "C" void kernel_launch(void* const* d_in, const int* in_sizes, int n_in,
                              void* d_out, int out_size, void* d_ws, size_t ws_size,
                              hipStream_t stream) {
  const float* hidden = (const float*)d_in[0];
  const int*   pos    = (const int*)d_in[1];
  const float* Wq     = (const float*)d_in[2];
  const float* Wkva   = (const float*)d_in[3];
  const float* w_kvln = (const float*)d_in[4];
  const float* Wkvb   = (const float*)d_in[5];
  const float* Wo     = (const float*)d_in[6];
  const float* Wg     = (const float*)d_in[7];
  const float* Wu     = (const float*)d_in[8];
  const float* Wd     = (const float*)d_in[9];
  const float* w_ln1  = (const float*)d_in[10];
  const float* w_ln2  = (const float*)d_in[11];
  float* out = (float*)d_out;

  char* ws = (char*)d_ws;
  ushort* xn    = (ushort*)(ws);
  char*   R1    = ws + 16777216;
  ushort* qb    = (ushort*)(R1);
  float*  ckv   = (float*)(R1 + 25165824);
  ushort* cn    = (ushort*)(R1 + 34603008);
  ushort* kvb   = (ushort*)(R1 + 38797312);
  ushort* kpe   = (ushort*)(R1 + 72351744);
  ushort* attno = (ushort*)(R1 + 72876032);
  ushort* gb    = (ushort*)(R1);                    // (T,10944) aliases R1
  float*  h1    = (float*)(ws + 196083712);

  char* WSL = ws + 106430464;                       // 89,653,248 B slot region
  ushort* wq_bf   = (ushort*)(WSL);                 // 3072 rows; wkva contiguous after
  ushort* wkva_bf = (ushort*)(WSL + 12582912);      // 576 rows -> combined N=3648
  ushort* wkvb_bf = (ushort*)(WSL + 14942208);
  ushort* wo_bf   = (ushort*)(WSL + 19136512);
  ushort* wg_bf   = (ushort*)(WSL);                 // phase B
  ushort* wu_bf   = (ushort*)(WSL + 44826624);
  ushort* wd_bf   = (ushort*)(WSL + 44826624);      // reuses wu slot after up GEMM

  cvt_bf16<<<3072, 256, 0, stream>>>(Wq,   wq_bf,   786432);
  cvt_bf16<<<576,  256, 0, stream>>>(Wkva, wkva_bf, 147456);
  cvt_bf16<<<1024, 256, 0, stream>>>(Wkvb, wkvb_bf, 262144);
  cvt_bf16<<<2048, 256, 0, stream>>>(Wo,   wo_bf,   524288);
  cvt_bf16<<<10944, 256, 0, stream>>>(Wu,  wu_bf,   2801664);

  rms_bf16<<<4096, 256, 0, stream>>>(hidden, 2048, 2048, 1.f / 2048.f, w_ln1, xn, 2048);
  // merged q + ckv projection (N = 3072 + 576 = 3648, weights contiguous)
  gemm_as<4><<<dim3(32, 29), 256, 0, stream>>>(xn, wq_bf, qb, ckv, 4096, 3648, 2048);
  rms_bf16<<<4096, 256, 0, stream>>>(ckv, 576, 512, 1.f / 512.f, w_kvln, cn, 512);
  gemm_as<0><<<dim3(32, 32), 256, 0, stream>>>(cn, wkvb_bf, kvb, nullptr, 4096, 4096, 512);
  rope_kernel<<<4096, 64, 0, stream>>>(qb, ckv, pos, kpe);
  attn_mfma<<<dim3(16, 32), 256, 0, stream>>>(qb, kvb, kpe, attno);
  gemm_as<2><<<dim3(32, 16), 256, 0, stream>>>(attno, wo_bf, h1, hidden, 4096, 2048, 2048);
  rms_bf16<<<4096, 256, 0, stream>>>(h1, 2048, 2048, 1.f / 2048.f, w_ln2, xn, 2048);

  cvt_bf16<<<10944, 256, 0, stream>>>(Wg, wg_bf, 2801664);
  gemm_as<0><<<dim3(32, 86), 256, 0, stream>>>(xn, wg_bf, gb, nullptr, 4096, 10944, 2048);
  gemm_as<3><<<dim3(32, 86), 256, 0, stream>>>(xn, wu_bf, gb, gb, 4096, 10944, 2048);
  cvt_bf16<<<10944, 256, 0, stream>>>(Wd, wd_bf, 2801664);
  gemm_as<2><<<dim3(32, 16), 256, 0, stream>>>(gb, wd_bf, out, h1, 4096, 2048, 10944);
}